// Round 1
// baseline (497.614 us; speedup 1.0000x reference)
//
#include <hip/hip_runtime.h>
#include <cstddef>
#include <cmath>

// ---------------------------------------------------------------------------
// SWGAT layer:
//   z = h @ W_fc.T                       [N,128]
//   e = leaky_relu(a1[src] + a2[dst]);  e==0 -> -1000
//   segment softmax over dst, out[w] = sum alpha * z[src]
// Strategy: fp32 tiled GEMM -> per-node attn scalars -> CSR by dst -> one
// wave per dst node for softmax + aggregation (no float atomics anywhere).
// ---------------------------------------------------------------------------

#define IN_DIM  256
#define OUT_DIM 128

// --- K0: transpose W_fc [128,256] -> Wt [256,128] ---------------------------
__global__ void transpose_w_kernel(const float* __restrict__ wfc, float* __restrict__ wt) {
    int i = blockIdx.x * 256 + threadIdx.x;           // over 128*256 = 32768
    if (i < OUT_DIM * IN_DIM) {
        int o = i >> 8;          // 0..127
        int k = i & 255;         // 0..255
        wt[k * OUT_DIM + o] = wfc[i];
    }
}

// --- K1: z = h @ W_fc.T  (fp32, 64x128 block tile, KB=32) -------------------
#define KB 32
__global__ __launch_bounds__(256) void gemm_kernel(const float* __restrict__ h,
                                                   const float* __restrict__ wt,
                                                   float* __restrict__ z, int M) {
    __shared__ float As[64][36];        // stride 36 floats = 144B (16B aligned, breaks pow2 banks)
    __shared__ float Bs[KB][OUT_DIM];   // [k][o]

    const int m0 = blockIdx.x * 64;
    const int t  = threadIdx.x;
    const int tx = t & 31;              // col group: cols tx*4 .. tx*4+3
    const int ty = t >> 5;              // row group: rows ty*8 .. ty*8+7

    float acc[8][4] = {};

    for (int k0 = 0; k0 < IN_DIM; k0 += KB) {
        // stage A: 64 rows x 32 k  = 512 float4, 2 per thread
#pragma unroll
        for (int i = 0; i < 2; ++i) {
            int l   = t + i * 256;
            int row = l >> 3;
            int f4  = l & 7;
            float4 v = make_float4(0.f, 0.f, 0.f, 0.f);
            if (m0 + row < M)
                v = *(const float4*)(h + (size_t)(m0 + row) * IN_DIM + k0 + f4 * 4);
            *(float4*)&As[row][f4 * 4] = v;
        }
        // stage B: 32 k x 128 o = 1024 float4 /4... (32*128/4 = 1024 float4, 4/thread)
#pragma unroll
        for (int i = 0; i < 4; ++i) {
            int l  = t + i * 256;
            int kk = l >> 5;
            int f4 = l & 31;
            float4 v = *(const float4*)(wt + (size_t)(k0 + kk) * OUT_DIM + f4 * 4);
            *(float4*)&Bs[kk][f4 * 4] = v;
        }
        __syncthreads();
#pragma unroll
        for (int kk = 0; kk < KB; ++kk) {
            float4 b = *(const float4*)&Bs[kk][tx * 4];
#pragma unroll
            for (int r = 0; r < 8; ++r) {
                float a = As[ty * 8 + r][kk];
                acc[r][0] += a * b.x;
                acc[r][1] += a * b.y;
                acc[r][2] += a * b.z;
                acc[r][3] += a * b.w;
            }
        }
        __syncthreads();
    }
#pragma unroll
    for (int r = 0; r < 8; ++r) {
        int row = m0 + ty * 8 + r;
        if (row < M)
            *(float4*)(z + (size_t)row * OUT_DIM + tx * 4) =
                make_float4(acc[r][0], acc[r][1], acc[r][2], acc[r][3]);
    }
}

// --- K2: per-node attention scalars a1,a2 (one wave per node) ---------------
__global__ __launch_bounds__(256) void a1a2_kernel(const float* __restrict__ z,
                                                   const float* __restrict__ wattn,
                                                   float* __restrict__ a1,
                                                   float* __restrict__ a2, int N) {
    const int lane = threadIdx.x & 63;
    const int wid  = blockIdx.x * 4 + (threadIdx.x >> 6);
    const int nw   = gridDim.x * 4;
    const float2 w1 = ((const float2*)wattn)[lane];        // W_attn[0:128]
    const float2 w2 = ((const float2*)wattn)[64 + lane];   // W_attn[128:256]
    for (int i = wid; i < N; i += nw) {
        float2 zr = ((const float2*)(z + (size_t)i * OUT_DIM))[lane];
        float p1 = zr.x * w1.x + zr.y * w1.y;
        float p2 = zr.x * w2.x + zr.y * w2.y;
#pragma unroll
        for (int o = 32; o; o >>= 1) {
            p1 += __shfl_xor(p1, o);
            p2 += __shfl_xor(p2, o);
        }
        if (lane == 0) { a1[i] = p1; a2[i] = p2; }
    }
}

// --- K3: zero counts --------------------------------------------------------
__global__ void zero_int_kernel(int* __restrict__ p, int n) {
    int i = blockIdx.x * 256 + threadIdx.x;
    if (i < n) p[i] = 0;
}

// --- K4: histogram of dst ---------------------------------------------------
__global__ void hist_kernel(const int* __restrict__ dst, int* __restrict__ cnt, int E) {
    int i = blockIdx.x * 256 + threadIdx.x;
    if (i < E) atomicAdd(&cnt[dst[i]], 1);
}

// --- K5: exclusive scan (single block, 1024 threads) ------------------------
__global__ __launch_bounds__(1024) void scan_kernel(const int* __restrict__ cnt,
                                                    int* __restrict__ off,
                                                    int* __restrict__ cur,
                                                    int NW, int E) {
    __shared__ int part[1024];
    const int t = threadIdx.x;
    const int items = (NW + 1023) >> 10;
    const int base = t * items;
    int s = 0;
    for (int j = 0; j < items; ++j) {
        int idx = base + j;
        if (idx < NW) s += cnt[idx];
    }
    part[t] = s;
    __syncthreads();
    // Hillis-Steele inclusive scan over 1024 partials
    for (int d = 1; d < 1024; d <<= 1) {
        int v = (t >= d) ? part[t - d] : 0;
        __syncthreads();
        part[t] += v;
        __syncthreads();
    }
    int run = part[t] - s;   // exclusive prefix of this thread's chunk
    for (int j = 0; j < items; ++j) {
        int idx = base + j;
        if (idx < NW) {
            off[idx] = run;
            cur[idx] = run;
            run += cnt[idx];
        }
    }
    if (t == 0) off[NW] = E;
}

// --- K6: scatter edges into CSR order, computing masked leaky scores --------
__global__ void scatter_kernel(const int* __restrict__ src, const int* __restrict__ dst,
                               const float* __restrict__ a1, const float* __restrict__ a2,
                               int* __restrict__ cur, int* __restrict__ esrc,
                               float* __restrict__ evals, int E) {
    int i = blockIdx.x * 256 + threadIdx.x;
    if (i >= E) return;
    int s = src[i];
    int d = dst[i];
    float x = a1[s] + a2[d];
    float e = x > 0.f ? x : 0.01f * x;          // leaky_relu(0.01)
    if (e == 0.f) e = -1000.f;                  // DGL zero-mask emulation
    int pos = atomicAdd(&cur[d], 1);
    esrc[pos]  = s;
    evals[pos] = e;
}

// --- K7: per-dst softmax + weighted aggregation (one wave per dst) ----------
__global__ __launch_bounds__(256) void agg_kernel(const float* __restrict__ z,
                                                  const int* __restrict__ off,
                                                  const int* __restrict__ esrc,
                                                  const float* __restrict__ evals,
                                                  float* __restrict__ out, int NW) {
    const int lane = threadIdx.x & 63;
    const int w = blockIdx.x * 4 + (threadIdx.x >> 6);
    if (w >= NW) return;
    const int beg = off[w];
    const int end = off[w + 1];

    float mx = -INFINITY;
    for (int j = beg + lane; j < end; j += 64) mx = fmaxf(mx, evals[j]);
#pragma unroll
    for (int o = 32; o; o >>= 1) mx = fmaxf(mx, __shfl_xor(mx, o));

    float s = 0.f;
    for (int j = beg + lane; j < end; j += 64) s += __expf(evals[j] - mx);
#pragma unroll
    for (int o = 32; o; o >>= 1) s += __shfl_xor(s, o);

    const float inv = (end > beg) ? 1.0f / s : 0.f;

    float2 acc = make_float2(0.f, 0.f);
    for (int j = beg; j < end; ++j) {
        int   sidx = esrc[j];                     // wave-uniform (broadcast load)
        float wgt  = __expf(evals[j] - mx) * inv; // wave-uniform
        float2 zr  = ((const float2*)(z + (size_t)sidx * OUT_DIM))[lane];
        acc.x += wgt * zr.x;
        acc.y += wgt * zr.y;
    }
    ((float2*)(out + (size_t)w * OUT_DIM))[lane] = acc;   // always written (zeros if empty)
}

// ---------------------------------------------------------------------------
extern "C" void kernel_launch(void* const* d_in, const int* in_sizes, int n_in,
                              void* d_out, int out_size, void* d_ws, size_t ws_size,
                              hipStream_t stream) {
    const float* h     = (const float*)d_in[0];
    const int*   src   = (const int*)d_in[1];
    const int*   dst   = (const int*)d_in[2];
    const float* wfc   = (const float*)d_in[3];
    const float* wattn = (const float*)d_in[4];
    float*       out   = (float*)d_out;

    const int N  = in_sizes[0] / IN_DIM;   // 100000
    const int E  = in_sizes[1];            // 500000
    const int NW = out_size / OUT_DIM;     // 50000

    // workspace layout (floats)
    float* z     = (float*)d_ws;                  // N*128
    float* a1    = z + (size_t)N * OUT_DIM;       // N
    float* a2    = a1 + N;                        // N
    float* wt    = a2 + N;                        // 256*128
    int*   cnt   = (int*)(wt + IN_DIM * OUT_DIM); // NW
    int*   off   = cnt + NW;                      // NW+1
    int*   cur   = off + NW + 1;                  // NW
    int*   esrc  = cur + NW;                      // E
    float* evals = (float*)(esrc + E);            // E

    transpose_w_kernel<<<(OUT_DIM * IN_DIM + 255) / 256, 256, 0, stream>>>(wfc, wt);
    gemm_kernel<<<(N + 63) / 64, 256, 0, stream>>>(h, wt, z, N);
    a1a2_kernel<<<512, 256, 0, stream>>>(z, wattn, a1, a2, N);
    zero_int_kernel<<<(NW + 255) / 256, 256, 0, stream>>>(cnt, NW);
    hist_kernel<<<(E + 255) / 256, 256, 0, stream>>>(dst, cnt, E);
    scan_kernel<<<1, 1024, 0, stream>>>(cnt, off, cur, NW, E);
    scatter_kernel<<<(E + 255) / 256, 256, 0, stream>>>(src, dst, a1, a2, cur, esrc, evals, E);
    agg_kernel<<<(NW + 3) / 4, 256, 0, stream>>>(z, off, esrc, evals, out, NW);
}

// Round 2
// 361.741 us; speedup vs baseline: 1.3756x; 1.3756x over previous
//
#include <hip/hip_runtime.h>
#include <cstddef>
#include <cmath>

// ---------------------------------------------------------------------------
// SWGAT layer:
//   z = h @ W_fc.T                       [N,128]
//   e = leaky_relu(a1[src] + a2[dst]);  e==0 -> -1000
//   segment softmax over dst, out[w] = sum alpha * z[src]
// R2: multi-block scan (R1's single-block scan was 128 us, 26% of total);
//     a1/a2 fused into GEMM epilogue (z row already in registers).
// ---------------------------------------------------------------------------

#define IN_DIM  256
#define OUT_DIM 128

// --- K0: transpose W_fc [128,256] -> Wt [256,128] ---------------------------
__global__ void transpose_w_kernel(const float* __restrict__ wfc, float* __restrict__ wt) {
    int i = blockIdx.x * 256 + threadIdx.x;           // over 128*256 = 32768
    if (i < OUT_DIM * IN_DIM) {
        int o = i >> 8;          // 0..127
        int k = i & 255;         // 0..255
        wt[k * OUT_DIM + o] = wfc[i];
    }
}

// --- K1: z = h @ W_fc.T  (fp32, 64x128 block tile, KB=32) + fused a1/a2 -----
#define KB 32
__global__ __launch_bounds__(256) void gemm_kernel(const float* __restrict__ h,
                                                   const float* __restrict__ wt,
                                                   const float* __restrict__ wattn,
                                                   float* __restrict__ z,
                                                   float* __restrict__ a1,
                                                   float* __restrict__ a2, int M) {
    __shared__ float As[64][36];        // +4 pad breaks pow2 bank stride
    __shared__ float Bs[KB][OUT_DIM];   // [k][o]

    const int m0 = blockIdx.x * 64;
    const int t  = threadIdx.x;
    const int tx = t & 31;              // col group: cols tx*4 .. tx*4+3
    const int ty = t >> 5;              // row group: rows ty*8 .. ty*8+7

    // attention weight slices for this thread's 4 columns (loaded early)
    const float4 w1 = *(const float4*)(wattn + tx * 4);            // W_attn[0:128]
    const float4 w2 = *(const float4*)(wattn + OUT_DIM + tx * 4);  // W_attn[128:256]

    float acc[8][4] = {};

    for (int k0 = 0; k0 < IN_DIM; k0 += KB) {
        // stage A: 64 rows x 32 k = 512 float4, 2 per thread
#pragma unroll
        for (int i = 0; i < 2; ++i) {
            int l   = t + i * 256;
            int row = l >> 3;
            int f4  = l & 7;
            float4 v = make_float4(0.f, 0.f, 0.f, 0.f);
            if (m0 + row < M)
                v = *(const float4*)(h + (size_t)(m0 + row) * IN_DIM + k0 + f4 * 4);
            *(float4*)&As[row][f4 * 4] = v;
        }
        // stage B: 32 k x 128 o = 1024 float4, 4 per thread
#pragma unroll
        for (int i = 0; i < 4; ++i) {
            int l  = t + i * 256;
            int kk = l >> 5;
            int f4 = l & 31;
            float4 v = *(const float4*)(wt + (size_t)(k0 + kk) * OUT_DIM + f4 * 4);
            *(float4*)&Bs[kk][f4 * 4] = v;
        }
        __syncthreads();
#pragma unroll
        for (int kk = 0; kk < KB; ++kk) {
            float4 b = *(const float4*)&Bs[kk][tx * 4];
#pragma unroll
            for (int r = 0; r < 8; ++r) {
                float a = As[ty * 8 + r][kk];
                acc[r][0] += a * b.x;
                acc[r][1] += a * b.y;
                acc[r][2] += a * b.z;
                acc[r][3] += a * b.w;
            }
        }
        __syncthreads();
    }

    // epilogue: write z + fused a1/a2 (reduce across the 32-lane col group;
    // same-ty threads are contiguous 32 lanes, so shfl_xor<=16 stays inside)
#pragma unroll
    for (int r = 0; r < 8; ++r) {
        int row = m0 + ty * 8 + r;
        float p1 = acc[r][0] * w1.x + acc[r][1] * w1.y + acc[r][2] * w1.z + acc[r][3] * w1.w;
        float p2 = acc[r][0] * w2.x + acc[r][1] * w2.y + acc[r][2] * w2.z + acc[r][3] * w2.w;
#pragma unroll
        for (int o = 16; o; o >>= 1) {
            p1 += __shfl_xor(p1, o);
            p2 += __shfl_xor(p2, o);
        }
        if (row < M) {
            *(float4*)(z + (size_t)row * OUT_DIM + tx * 4) =
                make_float4(acc[r][0], acc[r][1], acc[r][2], acc[r][3]);
            if (tx == 0) { a1[row] = p1; a2[row] = p2; }
        }
    }
}

// --- K3: zero counts --------------------------------------------------------
__global__ void zero_int_kernel(int* __restrict__ p, int n) {
    int i = blockIdx.x * 256 + threadIdx.x;
    if (i < n) p[i] = 0;
}

// --- K4: histogram of dst ---------------------------------------------------
__global__ void hist_kernel(const int* __restrict__ dst, int* __restrict__ cnt, int E) {
    int i = blockIdx.x * 256 + threadIdx.x;
    if (i < E) atomicAdd(&cnt[dst[i]], 1);
}

// --- K5a: per-block reduce of cnt -> bsum[196] ------------------------------
__global__ __launch_bounds__(256) void scan_reduce_kernel(const int* __restrict__ cnt,
                                                          int* __restrict__ bsum, int NW) {
    __shared__ int sm[4];
    const int t = threadIdx.x;
    const int i = blockIdx.x * 256 + t;
    int v = (i < NW) ? cnt[i] : 0;
#pragma unroll
    for (int o = 32; o; o >>= 1) v += __shfl_xor(v, o);
    if ((t & 63) == 0) sm[t >> 6] = v;
    __syncthreads();
    if (t == 0) bsum[blockIdx.x] = sm[0] + sm[1] + sm[2] + sm[3];
}

// --- K5b: exclusive scan of <=256 block partials (one block) ----------------
__global__ __launch_bounds__(256) void scan_partials_kernel(const int* __restrict__ bsum,
                                                            int* __restrict__ bpre, int nb,
                                                            int* __restrict__ off, int NW, int E) {
    __shared__ int sm[256];
    const int t = threadIdx.x;
    int v = (t < nb) ? bsum[t] : 0;
    sm[t] = v;
    __syncthreads();
    for (int d = 1; d < 256; d <<= 1) {
        int u = (t >= d) ? sm[t - d] : 0;
        __syncthreads();
        sm[t] += u;
        __syncthreads();
    }
    if (t < nb) bpre[t] = sm[t] - v;   // exclusive prefix of block t
    if (t == 0) off[NW] = E;
}

// --- K5c: block-local exclusive scan + block offset -> off, cur -------------
__global__ __launch_bounds__(256) void scan_final_kernel(const int* __restrict__ cnt,
                                                         const int* __restrict__ bpre,
                                                         int* __restrict__ off,
                                                         int* __restrict__ cur, int NW) {
    __shared__ int sm[256];
    const int t = threadIdx.x;
    const int i = blockIdx.x * 256 + t;
    int v = (i < NW) ? cnt[i] : 0;
    sm[t] = v;
    __syncthreads();
    for (int d = 1; d < 256; d <<= 1) {
        int u = (t >= d) ? sm[t - d] : 0;
        __syncthreads();
        sm[t] += u;
        __syncthreads();
    }
    int ex = sm[t] - v + bpre[blockIdx.x];
    if (i < NW) { off[i] = ex; cur[i] = ex; }
}

// --- K6: scatter edges into CSR order, computing masked leaky scores --------
__global__ void scatter_kernel(const int* __restrict__ src, const int* __restrict__ dst,
                               const float* __restrict__ a1, const float* __restrict__ a2,
                               int* __restrict__ cur, int* __restrict__ esrc,
                               float* __restrict__ evals, int E) {
    int i = blockIdx.x * 256 + threadIdx.x;
    if (i >= E) return;
    int s = src[i];
    int d = dst[i];
    float x = a1[s] + a2[d];
    float e = x > 0.f ? x : 0.01f * x;          // leaky_relu(0.01)
    if (e == 0.f) e = -1000.f;                  // DGL zero-mask emulation
    int pos = atomicAdd(&cur[d], 1);
    esrc[pos]  = s;
    evals[pos] = e;
}

// --- K7: per-dst softmax + weighted aggregation (one wave per dst) ----------
__global__ __launch_bounds__(256) void agg_kernel(const float* __restrict__ z,
                                                  const int* __restrict__ off,
                                                  const int* __restrict__ esrc,
                                                  const float* __restrict__ evals,
                                                  float* __restrict__ out, int NW) {
    const int lane = threadIdx.x & 63;
    const int w = blockIdx.x * 4 + (threadIdx.x >> 6);
    if (w >= NW) return;
    const int beg = off[w];
    const int end = off[w + 1];

    float mx = -INFINITY;
    for (int j = beg + lane; j < end; j += 64) mx = fmaxf(mx, evals[j]);
#pragma unroll
    for (int o = 32; o; o >>= 1) mx = fmaxf(mx, __shfl_xor(mx, o));

    float s = 0.f;
    for (int j = beg + lane; j < end; j += 64) s += __expf(evals[j] - mx);
#pragma unroll
    for (int o = 32; o; o >>= 1) s += __shfl_xor(s, o);

    const float inv = (end > beg) ? 1.0f / s : 0.f;

    float2 acc = make_float2(0.f, 0.f);
    for (int j = beg; j < end; ++j) {
        int   sidx = esrc[j];                     // wave-uniform (broadcast load)
        float wgt  = __expf(evals[j] - mx) * inv; // wave-uniform
        float2 zr  = ((const float2*)(z + (size_t)sidx * OUT_DIM))[lane];
        acc.x += wgt * zr.x;
        acc.y += wgt * zr.y;
    }
    ((float2*)(out + (size_t)w * OUT_DIM))[lane] = acc;   // always written (zeros if empty)
}

// ---------------------------------------------------------------------------
extern "C" void kernel_launch(void* const* d_in, const int* in_sizes, int n_in,
                              void* d_out, int out_size, void* d_ws, size_t ws_size,
                              hipStream_t stream) {
    const float* h     = (const float*)d_in[0];
    const int*   src   = (const int*)d_in[1];
    const int*   dst   = (const int*)d_in[2];
    const float* wfc   = (const float*)d_in[3];
    const float* wattn = (const float*)d_in[4];
    float*       out   = (float*)d_out;

    const int N  = in_sizes[0] / IN_DIM;   // 100000
    const int E  = in_sizes[1];            // 500000
    const int NW = out_size / OUT_DIM;     // 50000
    const int nb = (NW + 255) / 256;       // 196 scan blocks (<=256 required)

    // workspace layout
    float* z     = (float*)d_ws;                  // N*128
    float* a1    = z + (size_t)N * OUT_DIM;       // N
    float* a2    = a1 + N;                        // N
    float* wt    = a2 + N;                        // 256*128
    int*   cnt   = (int*)(wt + IN_DIM * OUT_DIM); // NW
    int*   off   = cnt + NW;                      // NW+1
    int*   cur   = off + NW + 1;                  // NW
    int*   esrc  = cur + NW;                      // E
    float* evals = (float*)(esrc + E);            // E
    int*   bsum  = (int*)(evals + E);             // nb
    int*   bpre  = bsum + nb;                     // nb

    transpose_w_kernel<<<(OUT_DIM * IN_DIM + 255) / 256, 256, 0, stream>>>(wfc, wt);
    gemm_kernel<<<(N + 63) / 64, 256, 0, stream>>>(h, wt, wattn, z, a1, a2, N);
    zero_int_kernel<<<(NW + 255) / 256, 256, 0, stream>>>(cnt, NW);
    hist_kernel<<<(E + 255) / 256, 256, 0, stream>>>(dst, cnt, E);
    scan_reduce_kernel<<<nb, 256, 0, stream>>>(cnt, bsum, NW);
    scan_partials_kernel<<<1, 256, 0, stream>>>(bsum, bpre, nb, off, NW, E);
    scan_final_kernel<<<nb, 256, 0, stream>>>(cnt, bpre, off, cur, NW);
    scatter_kernel<<<(E + 255) / 256, 256, 0, stream>>>(src, dst, a1, a2, cur, esrc, evals, E);
    agg_kernel<<<(NW + 3) / 4, 256, 0, stream>>>(z, off, esrc, evals, out, NW);
}

// Round 3
// 325.613 us; speedup vs baseline: 1.5282x; 1.1110x over previous
//
#include <hip/hip_runtime.h>
#include <cstddef>
#include <cmath>

// ---------------------------------------------------------------------------
// SWGAT layer:
//   z = h @ W_fc.T                       [N,128]
//   e = leaky_relu(a1[src] + a2[dst]);  e==0 -> -1000
//   segment softmax over dst, out[w] = sum alpha * z[src]
// R3: GEMM -> f16 MFMA (fp32 gemm was LDS-issue-bound at 118us, VALUBusy 48%,
//     MfmaUtil 0). f16 over bf16: values are N(0,1)-scale (range safe) and
//     f16 mantissa keeps absmax ~1e-2 vs threshold 8.8e-2. W_fc is already
//     [out][k] = B[n][k], so the transpose kernel is gone. B LDS-resident
//     (64KB, XOR-swizzled); A staged per 32-k chunk with pad-40 rows.
// ---------------------------------------------------------------------------

#define IN_DIM  256
#define OUT_DIM 128

typedef _Float16 half4_t __attribute__((ext_vector_type(4)));
typedef _Float16 half8_t __attribute__((ext_vector_type(8)));
typedef float    f32x4   __attribute__((ext_vector_type(4)));

// --- K1: z = h @ W_fc.T via mfma_f32_16x16x32_f16 ---------------------------
// block: 512 thr = 8 waves, tile 128 rows x 128 cols.
// wave w: rows (w>>1)*32 .. +31, cols (w&1)*64 .. +63  (2 mi x 4 ni tiles)
__global__ __launch_bounds__(512, 4) void gemm_kernel(const float* __restrict__ h,
                                                      const float* __restrict__ wfc,
                                                      float* __restrict__ z, int M) {
    __shared__ _Float16 Bs[IN_DIM * OUT_DIM];   // 64 KB, swizzled granules of 8 f16
    __shared__ _Float16 As[128 * 40];           // 10 KB, row stride 40 (pad 8)

    const int t    = threadIdx.x;
    const int lane = t & 63;
    const int w    = t >> 6;          // 0..7
    const int wr   = w >> 1;          // row quarter 0..3
    const int wc   = w & 1;           // col half 0..1
    const int quad = lane >> 4;       // 0..3
    const int l15  = lane & 15;
    const int m0   = blockIdx.x * 128;

    // ---- stage B once: wfc[n][k] fp32 -> f16 granules (8 per thread) ----
#pragma unroll
    for (int i = 0; i < 8; ++i) {
        int idx = t + i * 512;        // 0..4095 granules
        int n   = idx >> 5;           // 0..127
        int kb  = idx & 31;           // granule of 8 k
        const float* p = wfc + (size_t)n * IN_DIM + kb * 8;
        float4 v0 = *(const float4*)p;
        float4 v1 = *(const float4*)(p + 4);
        half8_t hv = {(_Float16)v0.x, (_Float16)v0.y, (_Float16)v0.z, (_Float16)v0.w,
                      (_Float16)v1.x, (_Float16)v1.y, (_Float16)v1.z, (_Float16)v1.w};
        *(half8_t*)&Bs[(size_t)(n * 32 + (kb ^ (n & 7))) * 8] = hv;
    }

    f32x4 acc[2][4] = {};   // [mi][ni]

    for (int kc = 0; kc < 8; ++kc) {
        const int k0 = kc * 32;
        __syncthreads();   // previous-iter reads done (and B writes visible at kc=0)
        // ---- stage A: 128 rows x 32 k, 2 float4 per thread ----
#pragma unroll
        for (int i = 0; i < 2; ++i) {
            int idx = t + i * 512;    // 0..1023
            int row = idx >> 3;       // 0..127
            int f4  = idx & 7;        // k sub-chunk of 4
            float4 v = make_float4(0.f, 0.f, 0.f, 0.f);
            if (m0 + row < M)
                v = *(const float4*)(h + (size_t)(m0 + row) * IN_DIM + k0 + f4 * 4);
            half4_t hv = {(_Float16)v.x, (_Float16)v.y, (_Float16)v.z, (_Float16)v.w};
            *(half4_t*)&As[row * 40 + f4 * 4] = hv;
        }
        __syncthreads();
        // ---- fragments + MFMA ----
        half8_t a[2], b[4];
#pragma unroll
        for (int mi = 0; mi < 2; ++mi) {
            int row = wr * 32 + mi * 16 + l15;
            a[mi] = *(const half8_t*)&As[row * 40 + quad * 8];
        }
#pragma unroll
        for (int ni = 0; ni < 4; ++ni) {
            int n = wc * 64 + ni * 16 + l15;
            int g = (kc * 4 + quad) ^ (n & 7);
            b[ni] = *(const half8_t*)&Bs[(size_t)(n * 32 + g) * 8];
        }
#pragma unroll
        for (int mi = 0; mi < 2; ++mi)
#pragma unroll
            for (int ni = 0; ni < 4; ++ni)
                acc[mi][ni] = __builtin_amdgcn_mfma_f32_16x16x32_f16(a[mi], b[ni], acc[mi][ni], 0, 0, 0);
    }

    // ---- epilogue: C/D layout col=l15, row=quad*4+r ----
#pragma unroll
    for (int mi = 0; mi < 2; ++mi) {
#pragma unroll
        for (int r = 0; r < 4; ++r) {
            int row = m0 + wr * 32 + mi * 16 + quad * 4 + r;
            if (row < M) {
#pragma unroll
                for (int ni = 0; ni < 4; ++ni) {
                    int col = wc * 64 + ni * 16 + l15;
                    z[(size_t)row * OUT_DIM + col] = acc[mi][ni][r];
                }
            }
        }
    }
}

// --- K2: per-node attention scalars a1,a2 (one wave per node) ---------------
__global__ __launch_bounds__(256) void a1a2_kernel(const float* __restrict__ z,
                                                   const float* __restrict__ wattn,
                                                   float* __restrict__ a1,
                                                   float* __restrict__ a2, int N) {
    const int lane = threadIdx.x & 63;
    const int wid  = blockIdx.x * 4 + (threadIdx.x >> 6);
    const int nw   = gridDim.x * 4;
    const float2 w1 = ((const float2*)wattn)[lane];        // W_attn[0:128]
    const float2 w2 = ((const float2*)wattn)[64 + lane];   // W_attn[128:256]
    for (int i = wid; i < N; i += nw) {
        float2 zr = ((const float2*)(z + (size_t)i * OUT_DIM))[lane];
        float p1 = zr.x * w1.x + zr.y * w1.y;
        float p2 = zr.x * w2.x + zr.y * w2.y;
#pragma unroll
        for (int o = 32; o; o >>= 1) {
            p1 += __shfl_xor(p1, o);
            p2 += __shfl_xor(p2, o);
        }
        if (lane == 0) { a1[i] = p1; a2[i] = p2; }
    }
}

// --- K3: zero counts --------------------------------------------------------
__global__ void zero_int_kernel(int* __restrict__ p, int n) {
    int i = blockIdx.x * 256 + threadIdx.x;
    if (i < n) p[i] = 0;
}

// --- K4: histogram of dst ---------------------------------------------------
__global__ void hist_kernel(const int* __restrict__ dst, int* __restrict__ cnt, int E) {
    int i = blockIdx.x * 256 + threadIdx.x;
    if (i < E) atomicAdd(&cnt[dst[i]], 1);
}

// --- K5a: per-block reduce of cnt -> bsum[196] ------------------------------
__global__ __launch_bounds__(256) void scan_reduce_kernel(const int* __restrict__ cnt,
                                                          int* __restrict__ bsum, int NW) {
    __shared__ int sm[4];
    const int t = threadIdx.x;
    const int i = blockIdx.x * 256 + t;
    int v = (i < NW) ? cnt[i] : 0;
#pragma unroll
    for (int o = 32; o; o >>= 1) v += __shfl_xor(v, o);
    if ((t & 63) == 0) sm[t >> 6] = v;
    __syncthreads();
    if (t == 0) bsum[blockIdx.x] = sm[0] + sm[1] + sm[2] + sm[3];
}

// --- K5b: exclusive scan of <=256 block partials (one block) ----------------
__global__ __launch_bounds__(256) void scan_partials_kernel(const int* __restrict__ bsum,
                                                            int* __restrict__ bpre, int nb,
                                                            int* __restrict__ off, int NW, int E) {
    __shared__ int sm[256];
    const int t = threadIdx.x;
    int v = (t < nb) ? bsum[t] : 0;
    sm[t] = v;
    __syncthreads();
    for (int d = 1; d < 256; d <<= 1) {
        int u = (t >= d) ? sm[t - d] : 0;
        __syncthreads();
        sm[t] += u;
        __syncthreads();
    }
    if (t < nb) bpre[t] = sm[t] - v;   // exclusive prefix of block t
    if (t == 0) off[NW] = E;
}

// --- K5c: block-local exclusive scan + block offset -> off, cur -------------
__global__ __launch_bounds__(256) void scan_final_kernel(const int* __restrict__ cnt,
                                                         const int* __restrict__ bpre,
                                                         int* __restrict__ off,
                                                         int* __restrict__ cur, int NW) {
    __shared__ int sm[256];
    const int t = threadIdx.x;
    const int i = blockIdx.x * 256 + t;
    int v = (i < NW) ? cnt[i] : 0;
    sm[t] = v;
    __syncthreads();
    for (int d = 1; d < 256; d <<= 1) {
        int u = (t >= d) ? sm[t - d] : 0;
        __syncthreads();
        sm[t] += u;
        __syncthreads();
    }
    int ex = sm[t] - v + bpre[blockIdx.x];
    if (i < NW) { off[i] = ex; cur[i] = ex; }
}

// --- K6: scatter edges into CSR order, computing masked leaky scores --------
__global__ void scatter_kernel(const int* __restrict__ src, const int* __restrict__ dst,
                               const float* __restrict__ a1, const float* __restrict__ a2,
                               int* __restrict__ cur, int* __restrict__ esrc,
                               float* __restrict__ evals, int E) {
    int i = blockIdx.x * 256 + threadIdx.x;
    if (i >= E) return;
    int s = src[i];
    int d = dst[i];
    float x = a1[s] + a2[d];
    float e = x > 0.f ? x : 0.01f * x;          // leaky_relu(0.01)
    if (e == 0.f) e = -1000.f;                  // DGL zero-mask emulation
    int pos = atomicAdd(&cur[d], 1);
    esrc[pos]  = s;
    evals[pos] = e;
}

// --- K7: per-dst softmax + weighted aggregation (one wave per dst) ----------
__global__ __launch_bounds__(256) void agg_kernel(const float* __restrict__ z,
                                                  const int* __restrict__ off,
                                                  const int* __restrict__ esrc,
                                                  const float* __restrict__ evals,
                                                  float* __restrict__ out, int NW) {
    const int lane = threadIdx.x & 63;
    const int w = blockIdx.x * 4 + (threadIdx.x >> 6);
    if (w >= NW) return;
    const int beg = off[w];
    const int end = off[w + 1];

    float mx = -INFINITY;
    for (int j = beg + lane; j < end; j += 64) mx = fmaxf(mx, evals[j]);
#pragma unroll
    for (int o = 32; o; o >>= 1) mx = fmaxf(mx, __shfl_xor(mx, o));

    float s = 0.f;
    for (int j = beg + lane; j < end; j += 64) s += __expf(evals[j] - mx);
#pragma unroll
    for (int o = 32; o; o >>= 1) s += __shfl_xor(s, o);

    const float inv = (end > beg) ? 1.0f / s : 0.f;

    float2 acc = make_float2(0.f, 0.f);
    for (int j = beg; j < end; ++j) {
        int   sidx = esrc[j];                     // wave-uniform (broadcast load)
        float wgt  = __expf(evals[j] - mx) * inv; // wave-uniform
        float2 zr  = ((const float2*)(z + (size_t)sidx * OUT_DIM))[lane];
        acc.x += wgt * zr.x;
        acc.y += wgt * zr.y;
    }
    ((float2*)(out + (size_t)w * OUT_DIM))[lane] = acc;   // always written (zeros if empty)
}

// ---------------------------------------------------------------------------
extern "C" void kernel_launch(void* const* d_in, const int* in_sizes, int n_in,
                              void* d_out, int out_size, void* d_ws, size_t ws_size,
                              hipStream_t stream) {
    const float* h     = (const float*)d_in[0];
    const int*   src   = (const int*)d_in[1];
    const int*   dst   = (const int*)d_in[2];
    const float* wfc   = (const float*)d_in[3];
    const float* wattn = (const float*)d_in[4];
    float*       out   = (float*)d_out;

    const int N  = in_sizes[0] / IN_DIM;   // 100000
    const int E  = in_sizes[1];            // 500000
    const int NW = out_size / OUT_DIM;     // 50000
    const int nb = (NW + 255) / 256;       // 196 scan blocks (<=256 required)

    // workspace layout
    float* z     = (float*)d_ws;                  // N*128
    float* a1    = z + (size_t)N * OUT_DIM;       // N
    float* a2    = a1 + N;                        // N
    int*   cnt   = (int*)(a2 + N);                // NW
    int*   off   = cnt + NW;                      // NW+1
    int*   cur   = off + NW + 1;                  // NW
    int*   esrc  = cur + NW;                      // E
    float* evals = (float*)(esrc + E);            // E
    int*   bsum  = (int*)(evals + E);             // nb
    int*   bpre  = bsum + nb;                     // nb

    gemm_kernel<<<(N + 127) / 128, 512, 0, stream>>>(h, wfc, z, N);
    a1a2_kernel<<<512, 256, 0, stream>>>(z, wattn, a1, a2, N);
    zero_int_kernel<<<(NW + 255) / 256, 256, 0, stream>>>(cnt, NW);
    hist_kernel<<<(E + 255) / 256, 256, 0, stream>>>(dst, cnt, E);
    scan_reduce_kernel<<<nb, 256, 0, stream>>>(cnt, bsum, NW);
    scan_partials_kernel<<<1, 256, 0, stream>>>(bsum, bpre, nb, off, NW, E);
    scan_final_kernel<<<nb, 256, 0, stream>>>(cnt, bpre, off, cur, NW);
    scatter_kernel<<<(E + 255) / 256, 256, 0, stream>>>(src, dst, a1, a2, cur, esrc, evals, E);
    agg_kernel<<<(NW + 3) / 4, 256, 0, stream>>>(z, off, esrc, evals, out, NW);
}

// Round 4
// 279.168 us; speedup vs baseline: 1.7825x; 1.1664x over previous
//
#include <hip/hip_runtime.h>
#include <cstddef>
#include <cmath>

// ---------------------------------------------------------------------------
// SWGAT layer:
//   z = h @ W_fc.T                       [N,128]
//   e = leaky_relu(a1[src] + a2[dst]);  e==0 -> -1000
//   segment softmax over dst, out[w] = sum alpha * z[src]
// R4: agg_kernel was latency-bound (65us, VALUBusy 28%, HBM 25%): register-
//     resident softmax (deg<=64 fast path) + shfl-broadcast weights + 4-way
//     unrolled z-row loads for MLP. a1/a2 re-fused into MFMA gemm epilogue
//     (removes 51MB z re-read). cnt zeroed via hipMemsetAsync (launch count).
// ---------------------------------------------------------------------------

#define IN_DIM  256
#define OUT_DIM 128

typedef _Float16 half4_t __attribute__((ext_vector_type(4)));
typedef _Float16 half8_t __attribute__((ext_vector_type(8)));
typedef float    f32x4   __attribute__((ext_vector_type(4)));

// --- K1: z = h @ W_fc.T via mfma_f32_16x16x32_f16, fused a1/a2 --------------
// block: 512 thr = 8 waves, tile 128 rows x 128 cols.
// wave w: rows (w>>1)*32 .. +31, cols (w&1)*64 .. +63  (2 mi x 4 ni tiles)
__global__ __launch_bounds__(512, 4) void gemm_kernel(const float* __restrict__ h,
                                                      const float* __restrict__ wfc,
                                                      const float* __restrict__ wattn,
                                                      float* __restrict__ z,
                                                      float* __restrict__ a1,
                                                      float* __restrict__ a2, int M) {
    __shared__ _Float16 Bs[IN_DIM * OUT_DIM];   // 64 KB, swizzled granules of 8 f16
    __shared__ _Float16 As[128 * 40];           // 10 KB, row stride 40 (pad 8)
    __shared__ float    pa[128][4];             // 2 KB: a1 half0, a1 half1, a2 h0, a2 h1

    const int t    = threadIdx.x;
    const int lane = t & 63;
    const int w    = t >> 6;          // 0..7
    const int wr   = w >> 1;          // row quarter 0..3
    const int wc   = w & 1;           // col half 0..1
    const int quad = lane >> 4;       // 0..3
    const int l15  = lane & 15;
    const int m0   = blockIdx.x * 128;

    // ---- stage B once: wfc[n][k] fp32 -> f16 granules (8 per thread) ----
#pragma unroll
    for (int i = 0; i < 8; ++i) {
        int idx = t + i * 512;        // 0..4095 granules
        int n   = idx >> 5;           // 0..127
        int kb  = idx & 31;           // granule of 8 k
        const float* p = wfc + (size_t)n * IN_DIM + kb * 8;
        float4 v0 = *(const float4*)p;
        float4 v1 = *(const float4*)(p + 4);
        half8_t hv = {(_Float16)v0.x, (_Float16)v0.y, (_Float16)v0.z, (_Float16)v0.w,
                      (_Float16)v1.x, (_Float16)v1.y, (_Float16)v1.z, (_Float16)v1.w};
        *(half8_t*)&Bs[(size_t)(n * 32 + (kb ^ (n & 7))) * 8] = hv;
    }

    f32x4 acc[2][4] = {};   // [mi][ni]

    for (int kc = 0; kc < 8; ++kc) {
        const int k0 = kc * 32;
        __syncthreads();   // previous-iter reads done (and B writes visible at kc=0)
        // ---- stage A: 128 rows x 32 k, 2 float4 per thread ----
#pragma unroll
        for (int i = 0; i < 2; ++i) {
            int idx = t + i * 512;    // 0..1023
            int row = idx >> 3;       // 0..127
            int f4  = idx & 7;        // k sub-chunk of 4
            float4 v = make_float4(0.f, 0.f, 0.f, 0.f);
            if (m0 + row < M)
                v = *(const float4*)(h + (size_t)(m0 + row) * IN_DIM + k0 + f4 * 4);
            half4_t hv = {(_Float16)v.x, (_Float16)v.y, (_Float16)v.z, (_Float16)v.w};
            *(half4_t*)&As[row * 40 + f4 * 4] = hv;
        }
        __syncthreads();
        // ---- fragments + MFMA ----
        half8_t a[2], b[4];
#pragma unroll
        for (int mi = 0; mi < 2; ++mi) {
            int row = wr * 32 + mi * 16 + l15;
            a[mi] = *(const half8_t*)&As[row * 40 + quad * 8];
        }
#pragma unroll
        for (int ni = 0; ni < 4; ++ni) {
            int n = wc * 64 + ni * 16 + l15;
            int g = (kc * 4 + quad) ^ (n & 7);
            b[ni] = *(const half8_t*)&Bs[(size_t)(n * 32 + g) * 8];
        }
#pragma unroll
        for (int mi = 0; mi < 2; ++mi)
#pragma unroll
            for (int ni = 0; ni < 4; ++ni)
                acc[mi][ni] = __builtin_amdgcn_mfma_f32_16x16x32_f16(a[mi], b[ni], acc[mi][ni], 0, 0, 0);
    }

    // ---- attention-weight slice for this lane's 4 columns ----
    float w1v[4], w2v[4];
#pragma unroll
    for (int ni = 0; ni < 4; ++ni) {
        int col = wc * 64 + ni * 16 + l15;
        w1v[ni] = wattn[col];
        w2v[ni] = wattn[OUT_DIM + col];
    }

    // ---- epilogue: C/D layout col=l15, row=quad*4+r; z write + a1/a2 -------
#pragma unroll
    for (int mi = 0; mi < 2; ++mi) {
#pragma unroll
        for (int r = 0; r < 4; ++r) {
            int lr  = wr * 32 + mi * 16 + quad * 4 + r;   // local row
            int row = m0 + lr;
            float p1 = acc[mi][0][r] * w1v[0] + acc[mi][1][r] * w1v[1]
                     + acc[mi][2][r] * w1v[2] + acc[mi][3][r] * w1v[3];
            float p2 = acc[mi][0][r] * w2v[0] + acc[mi][1][r] * w2v[1]
                     + acc[mi][2][r] * w2v[2] + acc[mi][3][r] * w2v[3];
#pragma unroll
            for (int o = 8; o; o >>= 1) {       // reduce across 16-lane col group
                p1 += __shfl_xor(p1, o);
                p2 += __shfl_xor(p2, o);
            }
            if (l15 == 0) { pa[lr][wc] = p1; pa[lr][2 + wc] = p2; }
            if (row < M) {
#pragma unroll
                for (int ni = 0; ni < 4; ++ni) {
                    int col = wc * 64 + ni * 16 + l15;
                    z[(size_t)row * OUT_DIM + col] = acc[mi][ni][r];
                }
            }
        }
    }
    __syncthreads();
    if (t < 128 && m0 + t < M) {
        a1[m0 + t] = pa[t][0] + pa[t][1];
        a2[m0 + t] = pa[t][2] + pa[t][3];
    }
}

// --- K4: histogram of dst ---------------------------------------------------
__global__ void hist_kernel(const int* __restrict__ dst, int* __restrict__ cnt, int E) {
    int i = blockIdx.x * 256 + threadIdx.x;
    if (i < E) atomicAdd(&cnt[dst[i]], 1);
}

// --- K5a: per-block reduce of cnt -> bsum[196] ------------------------------
__global__ __launch_bounds__(256) void scan_reduce_kernel(const int* __restrict__ cnt,
                                                          int* __restrict__ bsum, int NW) {
    __shared__ int sm[4];
    const int t = threadIdx.x;
    const int i = blockIdx.x * 256 + t;
    int v = (i < NW) ? cnt[i] : 0;
#pragma unroll
    for (int o = 32; o; o >>= 1) v += __shfl_xor(v, o);
    if ((t & 63) == 0) sm[t >> 6] = v;
    __syncthreads();
    if (t == 0) bsum[blockIdx.x] = sm[0] + sm[1] + sm[2] + sm[3];
}

// --- K5b: exclusive scan of <=256 block partials (one block) ----------------
__global__ __launch_bounds__(256) void scan_partials_kernel(const int* __restrict__ bsum,
                                                            int* __restrict__ bpre, int nb,
                                                            int* __restrict__ off, int NW, int E) {
    __shared__ int sm[256];
    const int t = threadIdx.x;
    int v = (t < nb) ? bsum[t] : 0;
    sm[t] = v;
    __syncthreads();
    for (int d = 1; d < 256; d <<= 1) {
        int u = (t >= d) ? sm[t - d] : 0;
        __syncthreads();
        sm[t] += u;
        __syncthreads();
    }
    if (t < nb) bpre[t] = sm[t] - v;   // exclusive prefix of block t
    if (t == 0) off[NW] = E;
}

// --- K5c: block-local exclusive scan + block offset -> off, cur -------------
__global__ __launch_bounds__(256) void scan_final_kernel(const int* __restrict__ cnt,
                                                         const int* __restrict__ bpre,
                                                         int* __restrict__ off,
                                                         int* __restrict__ cur, int NW) {
    __shared__ int sm[256];
    const int t = threadIdx.x;
    const int i = blockIdx.x * 256 + t;
    int v = (i < NW) ? cnt[i] : 0;
    sm[t] = v;
    __syncthreads();
    for (int d = 1; d < 256; d <<= 1) {
        int u = (t >= d) ? sm[t - d] : 0;
        __syncthreads();
        sm[t] += u;
        __syncthreads();
    }
    int ex = sm[t] - v + bpre[blockIdx.x];
    if (i < NW) { off[i] = ex; cur[i] = ex; }
}

// --- K6: scatter edges into CSR order, computing masked leaky scores --------
__global__ void scatter_kernel(const int* __restrict__ src, const int* __restrict__ dst,
                               const float* __restrict__ a1, const float* __restrict__ a2,
                               int* __restrict__ cur, int* __restrict__ esrc,
                               float* __restrict__ evals, int E) {
    int i = blockIdx.x * 256 + threadIdx.x;
    if (i >= E) return;
    int s = src[i];
    int d = dst[i];
    float x = a1[s] + a2[d];
    float e = x > 0.f ? x : 0.01f * x;          // leaky_relu(0.01)
    if (e == 0.f) e = -1000.f;                  // DGL zero-mask emulation
    int pos = atomicAdd(&cur[d], 1);
    esrc[pos]  = s;
    evals[pos] = e;
}

// --- K7: per-dst softmax + weighted aggregation (one wave per dst) ----------
// Fast path (deg<=64): evals/esrc register-resident, weights broadcast by
// shfl, z-row loads unrolled x4 for memory-level parallelism.
__global__ __launch_bounds__(256) void agg_kernel(const float* __restrict__ z,
                                                  const int* __restrict__ off,
                                                  const int* __restrict__ esrc,
                                                  const float* __restrict__ evals,
                                                  float* __restrict__ out, int NW) {
    const int lane = threadIdx.x & 63;
    const int w = blockIdx.x * 4 + (threadIdx.x >> 6);
    if (w >= NW) return;
    const int beg = off[w];
    const int end = off[w + 1];
    const int cnt = end - beg;

    float2 acc = make_float2(0.f, 0.f);

    if (cnt <= 64) {
        float ev = (lane < cnt) ? evals[beg + lane] : -INFINITY;
        int   se = (lane < cnt) ? esrc[beg + lane] : 0;
        float mx = ev;
#pragma unroll
        for (int o = 32; o; o >>= 1) mx = fmaxf(mx, __shfl_xor(mx, o));
        float ex = (lane < cnt) ? __expf(ev - mx) : 0.f;
        float s = ex;
#pragma unroll
        for (int o = 32; o; o >>= 1) s += __shfl_xor(s, o);
        ex *= (cnt > 0) ? (1.0f / s) : 0.f;      // per-lane alpha

        int j = 0;
        for (; j + 4 <= cnt; j += 4) {
            int   s0 = __shfl(se, j),     s1 = __shfl(se, j + 1);
            int   s2 = __shfl(se, j + 2), s3 = __shfl(se, j + 3);
            float w0 = __shfl(ex, j),     w1 = __shfl(ex, j + 1);
            float w2 = __shfl(ex, j + 2), w3 = __shfl(ex, j + 3);
            float2 z0 = ((const float2*)(z + (size_t)s0 * OUT_DIM))[lane];
            float2 z1 = ((const float2*)(z + (size_t)s1 * OUT_DIM))[lane];
            float2 z2 = ((const float2*)(z + (size_t)s2 * OUT_DIM))[lane];
            float2 z3 = ((const float2*)(z + (size_t)s3 * OUT_DIM))[lane];
            acc.x += w0 * z0.x + w1 * z1.x + w2 * z2.x + w3 * z3.x;
            acc.y += w0 * z0.y + w1 * z1.y + w2 * z2.y + w3 * z3.y;
        }
        for (; j < cnt; ++j) {
            int   sj = __shfl(se, j);
            float wj = __shfl(ex, j);
            float2 zj = ((const float2*)(z + (size_t)sj * OUT_DIM))[lane];
            acc.x += wj * zj.x;
            acc.y += wj * zj.y;
        }
    } else {
        // rare fallback: degree > 64
        float mx = -INFINITY;
        for (int j = beg + lane; j < end; j += 64) mx = fmaxf(mx, evals[j]);
#pragma unroll
        for (int o = 32; o; o >>= 1) mx = fmaxf(mx, __shfl_xor(mx, o));
        float s = 0.f;
        for (int j = beg + lane; j < end; j += 64) s += __expf(evals[j] - mx);
#pragma unroll
        for (int o = 32; o; o >>= 1) s += __shfl_xor(s, o);
        const float inv = 1.0f / s;
        for (int j = beg; j < end; ++j) {
            int   sidx = esrc[j];
            float wgt  = __expf(evals[j] - mx) * inv;
            float2 zr  = ((const float2*)(z + (size_t)sidx * OUT_DIM))[lane];
            acc.x += wgt * zr.x;
            acc.y += wgt * zr.y;
        }
    }
    ((float2*)(out + (size_t)w * OUT_DIM))[lane] = acc;   // always written (zeros if empty)
}

// ---------------------------------------------------------------------------
extern "C" void kernel_launch(void* const* d_in, const int* in_sizes, int n_in,
                              void* d_out, int out_size, void* d_ws, size_t ws_size,
                              hipStream_t stream) {
    const float* h     = (const float*)d_in[0];
    const int*   src   = (const int*)d_in[1];
    const int*   dst   = (const int*)d_in[2];
    const float* wfc   = (const float*)d_in[3];
    const float* wattn = (const float*)d_in[4];
    float*       out   = (float*)d_out;

    const int N  = in_sizes[0] / IN_DIM;   // 100000
    const int E  = in_sizes[1];            // 500000
    const int NW = out_size / OUT_DIM;     // 50000
    const int nb = (NW + 255) / 256;       // 196 scan blocks (<=256 required)

    // workspace layout
    float* z     = (float*)d_ws;                  // N*128
    float* a1    = z + (size_t)N * OUT_DIM;       // N
    float* a2    = a1 + N;                        // N
    int*   cnt   = (int*)(a2 + N);                // NW
    int*   off   = cnt + NW;                      // NW+1
    int*   cur   = off + NW + 1;                  // NW
    int*   esrc  = cur + NW;                      // E
    float* evals = (float*)(esrc + E);            // E
    int*   bsum  = (int*)(evals + E);             // nb
    int*   bpre  = bsum + nb;                     // nb

    gemm_kernel<<<(N + 127) / 128, 512, 0, stream>>>(h, wfc, wattn, z, a1, a2, N);
    hipMemsetAsync(cnt, 0, (size_t)NW * sizeof(int), stream);
    hist_kernel<<<(E + 255) / 256, 256, 0, stream>>>(dst, cnt, E);
    scan_reduce_kernel<<<nb, 256, 0, stream>>>(cnt, bsum, NW);
    scan_partials_kernel<<<1, 256, 0, stream>>>(bsum, bpre, nb, off, NW, E);
    scan_final_kernel<<<nb, 256, 0, stream>>>(cnt, bpre, off, cur, NW);
    scatter_kernel<<<(E + 255) / 256, 256, 0, stream>>>(src, dst, a1, a2, cur, esrc, evals, E);
    agg_kernel<<<(NW + 3) / 4, 256, 0, stream>>>(z, off, esrc, evals, out, NW);
}

// Round 5
// 270.009 us; speedup vs baseline: 1.8430x; 1.0339x over previous
//
#include <hip/hip_runtime.h>
#include <cstddef>
#include <cmath>

// ---------------------------------------------------------------------------
// SWGAT layer:
//   z = h @ W_fc.T                       [N,128]
//   e = leaky_relu(a1[src] + a2[dst]);  e==0 -> -1000
//   segment softmax over dst, out[w] = sum alpha * z[src]
// R5: R4 gemm was barrier-bound (67us, MfmaUtil 3.5%, VALU 8%, HBM 19%).
//     New gemm: A-frags loaded straight from global (32B/lane contiguous),
//     B LDS-resident (one barrier total), K-loop barrier-FREE and fully
//     unrolled -> loads pipeline across chunks. Wave owns 16 rows x 128 cols
//     so a1/a2 reduce is intra-quad shfl only. z stored as f16 (halves gemm
//     write + agg read traffic; error budget: +~2e-3 vs threshold 8.8e-2).
// ---------------------------------------------------------------------------

#define IN_DIM  256
#define OUT_DIM 128

typedef _Float16 half2_t __attribute__((ext_vector_type(2)));
typedef _Float16 half8_t __attribute__((ext_vector_type(8)));
typedef float    f32x4   __attribute__((ext_vector_type(4)));

// --- K1: z = h @ W_fc.T via mfma_f32_16x16x32_f16, fused a1/a2, f16 z -------
// block: 512 thr = 8 waves, tile 128 rows. Wave w owns rows w*16..w*16+15,
// all 128 cols (8 ni tiles). A-frag: lane reads h[row][kc*32+quad*8..+7]
// (32B contiguous). B: whole W_fc as f16 in LDS, XOR-swizzled, staged once.
__global__ __launch_bounds__(512, 4) void gemm_kernel(const float* __restrict__ h,
                                                      const float* __restrict__ wfc,
                                                      const float* __restrict__ wattn,
                                                      _Float16* __restrict__ zh,
                                                      float* __restrict__ a1,
                                                      float* __restrict__ a2, int M) {
    __shared__ _Float16 Bs[IN_DIM * OUT_DIM];   // 64 KB, swizzled granules of 8 f16

    const int t    = threadIdx.x;
    const int lane = t & 63;
    const int w    = t >> 6;          // 0..7
    const int quad = lane >> 4;       // 0..3
    const int l15  = lane & 15;
    const int m0   = blockIdx.x * 128;

    // ---- stage B once: wfc[n][k] fp32 -> f16 granules (8 per thread) ----
#pragma unroll
    for (int i = 0; i < 8; ++i) {
        int idx = t + i * 512;        // 0..4095 granules
        int n   = idx >> 5;           // 0..127
        int kb  = idx & 31;           // granule of 8 k
        const float* p = wfc + (size_t)n * IN_DIM + kb * 8;
        float4 v0 = *(const float4*)p;
        float4 v1 = *(const float4*)(p + 4);
        half8_t hv = {(_Float16)v0.x, (_Float16)v0.y, (_Float16)v0.z, (_Float16)v0.w,
                      (_Float16)v1.x, (_Float16)v1.y, (_Float16)v1.z, (_Float16)v1.w};
        *(half8_t*)&Bs[(size_t)(n * 32 + (kb ^ (n & 7))) * 8] = hv;
    }
    __syncthreads();   // the ONLY block-wide barrier

    // lane's A row (clamped; OOB rows computed but never stored)
    const int lrow = w * 16 + l15;
    const int grow = (m0 + lrow < M) ? (m0 + lrow) : (M - 1);
    const float* arow = h + (size_t)grow * IN_DIM;

    f32x4 acc[8] = {};   // [ni]

#pragma unroll
    for (int kc = 0; kc < 8; ++kc) {
        // A-frag straight from global: 8 fp32 = 32 B contiguous per lane
        float4 v0 = *(const float4*)(arow + kc * 32 + quad * 8);
        float4 v1 = *(const float4*)(arow + kc * 32 + quad * 8 + 4);
        half8_t a = {(_Float16)v0.x, (_Float16)v0.y, (_Float16)v0.z, (_Float16)v0.w,
                     (_Float16)v1.x, (_Float16)v1.y, (_Float16)v1.z, (_Float16)v1.w};
#pragma unroll
        for (int ni = 0; ni < 8; ++ni) {
            int n = ni * 16 + l15;
            int g = (kc * 4 + quad) ^ (n & 7);
            half8_t b = *(const half8_t*)&Bs[(size_t)(n * 32 + g) * 8];
            acc[ni] = __builtin_amdgcn_mfma_f32_16x16x32_f16(a, b, acc[ni], 0, 0, 0);
        }
    }

    // ---- fused a1/a2: all 128 cols of a row live in this wave ----
    float w1v[8], w2v[8];
#pragma unroll
    for (int ni = 0; ni < 8; ++ni) {
        int col = ni * 16 + l15;
        w1v[ni] = wattn[col];
        w2v[ni] = wattn[OUT_DIM + col];
    }
#pragma unroll
    for (int r = 0; r < 4; ++r) {
        float p1 = 0.f, p2 = 0.f;
#pragma unroll
        for (int ni = 0; ni < 8; ++ni) {
            p1 += acc[ni][r] * w1v[ni];
            p2 += acc[ni][r] * w2v[ni];
        }
#pragma unroll
        for (int o = 8; o; o >>= 1) {       // reduce across the 16-lane col group
            p1 += __shfl_xor(p1, o);
            p2 += __shfl_xor(p2, o);
        }
        int row = m0 + w * 16 + quad * 4 + r;
        if (l15 == 0 && row < M) { a1[row] = p1; a2[row] = p2; }
    }

    // ---- z stores (f16): C/D layout col=l15 within tile, row=quad*4+r ----
#pragma unroll
    for (int r = 0; r < 4; ++r) {
        int row = m0 + w * 16 + quad * 4 + r;
        if (row < M) {
#pragma unroll
            for (int ni = 0; ni < 8; ++ni)
                zh[(size_t)row * OUT_DIM + ni * 16 + l15] = (_Float16)acc[ni][r];
        }
    }
}

// --- K4: histogram of dst ---------------------------------------------------
__global__ void hist_kernel(const int* __restrict__ dst, int* __restrict__ cnt, int E) {
    int i = blockIdx.x * 256 + threadIdx.x;
    if (i < E) atomicAdd(&cnt[dst[i]], 1);
}

// --- K5a: per-block reduce of cnt -> bsum[196] ------------------------------
__global__ __launch_bounds__(256) void scan_reduce_kernel(const int* __restrict__ cnt,
                                                          int* __restrict__ bsum, int NW) {
    __shared__ int sm[4];
    const int t = threadIdx.x;
    const int i = blockIdx.x * 256 + t;
    int v = (i < NW) ? cnt[i] : 0;
#pragma unroll
    for (int o = 32; o; o >>= 1) v += __shfl_xor(v, o);
    if ((t & 63) == 0) sm[t >> 6] = v;
    __syncthreads();
    if (t == 0) bsum[blockIdx.x] = sm[0] + sm[1] + sm[2] + sm[3];
}

// --- K5b: exclusive scan of <=256 block partials (one block) ----------------
__global__ __launch_bounds__(256) void scan_partials_kernel(const int* __restrict__ bsum,
                                                            int* __restrict__ bpre, int nb,
                                                            int* __restrict__ off, int NW, int E) {
    __shared__ int sm[256];
    const int t = threadIdx.x;
    int v = (t < nb) ? bsum[t] : 0;
    sm[t] = v;
    __syncthreads();
    for (int d = 1; d < 256; d <<= 1) {
        int u = (t >= d) ? sm[t - d] : 0;
        __syncthreads();
        sm[t] += u;
        __syncthreads();
    }
    if (t < nb) bpre[t] = sm[t] - v;   // exclusive prefix of block t
    if (t == 0) off[NW] = E;
}

// --- K5c: block-local exclusive scan + block offset -> off, cur -------------
__global__ __launch_bounds__(256) void scan_final_kernel(const int* __restrict__ cnt,
                                                         const int* __restrict__ bpre,
                                                         int* __restrict__ off,
                                                         int* __restrict__ cur, int NW) {
    __shared__ int sm[256];
    const int t = threadIdx.x;
    const int i = blockIdx.x * 256 + t;
    int v = (i < NW) ? cnt[i] : 0;
    sm[t] = v;
    __syncthreads();
    for (int d = 1; d < 256; d <<= 1) {
        int u = (t >= d) ? sm[t - d] : 0;
        __syncthreads();
        sm[t] += u;
        __syncthreads();
    }
    int ex = sm[t] - v + bpre[blockIdx.x];
    if (i < NW) { off[i] = ex; cur[i] = ex; }
}

// --- K6: scatter edges into CSR order, computing masked leaky scores --------
__global__ void scatter_kernel(const int* __restrict__ src, const int* __restrict__ dst,
                               const float* __restrict__ a1, const float* __restrict__ a2,
                               int* __restrict__ cur, int* __restrict__ esrc,
                               float* __restrict__ evals, int E) {
    int i = blockIdx.x * 256 + threadIdx.x;
    if (i >= E) return;
    int s = src[i];
    int d = dst[i];
    float x = a1[s] + a2[d];
    float e = x > 0.f ? x : 0.01f * x;          // leaky_relu(0.01)
    if (e == 0.f) e = -1000.f;                  // DGL zero-mask emulation
    int pos = atomicAdd(&cur[d], 1);
    esrc[pos]  = s;
    evals[pos] = e;
}

// --- K7: per-dst softmax + weighted aggregation (one wave per dst) ----------
// Fast path (deg<=64): evals/esrc register-resident, weights broadcast by
// shfl, z-row (f16, 256B) loads unrolled x4 for memory-level parallelism.
__global__ __launch_bounds__(256) void agg_kernel(const _Float16* __restrict__ zh,
                                                  const int* __restrict__ off,
                                                  const int* __restrict__ esrc,
                                                  const float* __restrict__ evals,
                                                  float* __restrict__ out, int NW) {
    const int lane = threadIdx.x & 63;
    const int w = blockIdx.x * 4 + (threadIdx.x >> 6);
    if (w >= NW) return;
    const int beg = off[w];
    const int end = off[w + 1];
    const int cnt = end - beg;

    float2 acc = make_float2(0.f, 0.f);

    if (cnt <= 64) {
        float ev = (lane < cnt) ? evals[beg + lane] : -INFINITY;
        int   se = (lane < cnt) ? esrc[beg + lane] : 0;
        float mx = ev;
#pragma unroll
        for (int o = 32; o; o >>= 1) mx = fmaxf(mx, __shfl_xor(mx, o));
        float ex = (lane < cnt) ? __expf(ev - mx) : 0.f;
        float s = ex;
#pragma unroll
        for (int o = 32; o; o >>= 1) s += __shfl_xor(s, o);
        ex *= (cnt > 0) ? (1.0f / s) : 0.f;      // per-lane alpha

        int j = 0;
        for (; j + 4 <= cnt; j += 4) {
            int   s0 = __shfl(se, j),     s1 = __shfl(se, j + 1);
            int   s2 = __shfl(se, j + 2), s3 = __shfl(se, j + 3);
            float w0 = __shfl(ex, j),     w1 = __shfl(ex, j + 1);
            float w2 = __shfl(ex, j + 2), w3 = __shfl(ex, j + 3);
            half2_t z0 = *(const half2_t*)(zh + (size_t)s0 * OUT_DIM + lane * 2);
            half2_t z1 = *(const half2_t*)(zh + (size_t)s1 * OUT_DIM + lane * 2);
            half2_t z2 = *(const half2_t*)(zh + (size_t)s2 * OUT_DIM + lane * 2);
            half2_t z3 = *(const half2_t*)(zh + (size_t)s3 * OUT_DIM + lane * 2);
            acc.x += w0 * (float)z0[0] + w1 * (float)z1[0] + w2 * (float)z2[0] + w3 * (float)z3[0];
            acc.y += w0 * (float)z0[1] + w1 * (float)z1[1] + w2 * (float)z2[1] + w3 * (float)z3[1];
        }
        for (; j < cnt; ++j) {
            int   sj = __shfl(se, j);
            float wj = __shfl(ex, j);
            half2_t zj = *(const half2_t*)(zh + (size_t)sj * OUT_DIM + lane * 2);
            acc.x += wj * (float)zj[0];
            acc.y += wj * (float)zj[1];
        }
    } else {
        // rare fallback: degree > 64
        float mx = -INFINITY;
        for (int j = beg + lane; j < end; j += 64) mx = fmaxf(mx, evals[j]);
#pragma unroll
        for (int o = 32; o; o >>= 1) mx = fmaxf(mx, __shfl_xor(mx, o));
        float s = 0.f;
        for (int j = beg + lane; j < end; j += 64) s += __expf(evals[j] - mx);
#pragma unroll
        for (int o = 32; o; o >>= 1) s += __shfl_xor(s, o);
        const float inv = 1.0f / s;
        for (int j = beg; j < end; ++j) {
            int   sidx = esrc[j];
            float wgt  = __expf(evals[j] - mx) * inv;
            half2_t zr = *(const half2_t*)(zh + (size_t)sidx * OUT_DIM + lane * 2);
            acc.x += wgt * (float)zr[0];
            acc.y += wgt * (float)zr[1];
        }
    }
    ((float2*)(out + (size_t)w * OUT_DIM))[lane] = acc;   // always written (zeros if empty)
}

// ---------------------------------------------------------------------------
extern "C" void kernel_launch(void* const* d_in, const int* in_sizes, int n_in,
                              void* d_out, int out_size, void* d_ws, size_t ws_size,
                              hipStream_t stream) {
    const float* h     = (const float*)d_in[0];
    const int*   src   = (const int*)d_in[1];
    const int*   dst   = (const int*)d_in[2];
    const float* wfc   = (const float*)d_in[3];
    const float* wattn = (const float*)d_in[4];
    float*       out   = (float*)d_out;

    const int N  = in_sizes[0] / IN_DIM;   // 100000
    const int E  = in_sizes[1];            // 500000
    const int NW = out_size / OUT_DIM;     // 50000
    const int nb = (NW + 255) / 256;       // 196 scan blocks (<=256 required)

    // workspace layout
    _Float16* zh = (_Float16*)d_ws;               // N*128 f16
    float* a1    = (float*)(zh + (size_t)N * OUT_DIM);  // N
    float* a2    = a1 + N;                        // N
    int*   cnt   = (int*)(a2 + N);                // NW
    int*   off   = cnt + NW;                      // NW+1
    int*   cur   = off + NW + 1;                  // NW
    int*   esrc  = cur + NW;                      // E
    float* evals = (float*)(esrc + E);            // E
    int*   bsum  = (int*)(evals + E);             // nb
    int*   bpre  = bsum + nb;                     // nb

    gemm_kernel<<<(N + 127) / 128, 512, 0, stream>>>(h, wfc, wattn, zh, a1, a2, N);
    hipMemsetAsync(cnt, 0, (size_t)NW * sizeof(int), stream);
    hist_kernel<<<(E + 255) / 256, 256, 0, stream>>>(dst, cnt, E);
    scan_reduce_kernel<<<nb, 256, 0, stream>>>(cnt, bsum, NW);
    scan_partials_kernel<<<1, 256, 0, stream>>>(bsum, bpre, nb, off, NW, E);
    scan_final_kernel<<<nb, 256, 0, stream>>>(cnt, bpre, off, cur, NW);
    scatter_kernel<<<(E + 255) / 256, 256, 0, stream>>>(src, dst, a1, a2, cur, esrc, evals, E);
    agg_kernel<<<(NW + 3) / 4, 256, 0, stream>>>(zh, off, esrc, evals, out, NW);
}

// Round 6
// 264.607 us; speedup vs baseline: 1.8806x; 1.0204x over previous
//
#include <hip/hip_runtime.h>
#include <cstddef>
#include <cmath>

// ---------------------------------------------------------------------------
// SWGAT layer:
//   z = h @ W_fc.T                       [N,128]
//   e = leaky_relu(a1[src] + a2[dst]);  e==0 -> -1000
//   segment softmax over dst, out[w] = sum alpha * z[src]
// R6: R5 gemm was VMEM-throughput-bound (60us): every block re-staged W_fc as
//     fp32 (100MB L2 traffic) and the 782-block grid had a 1.53-round tail.
//     Now: W pre-converted to f16 + pre-swizzled once (wconv), gemm blocks do
//     a 64KB linear f16 copy; 256-row blocks (391 total, single round, wave
//     owns 2x16 rows) halve W traffic again and amortize b-frag ds_reads.
// ---------------------------------------------------------------------------

#define IN_DIM  256
#define OUT_DIM 128

typedef _Float16 half2_t __attribute__((ext_vector_type(2)));
typedef _Float16 half8_t __attribute__((ext_vector_type(8)));
typedef float    f32x4   __attribute__((ext_vector_type(4)));

// --- K0: convert W_fc fp32 -> f16, swizzled granule layout ------------------
// granule g = n*32 + (kb ^ (n&7)) holds wfc[n][kb*8 .. kb*8+7]
__global__ __launch_bounds__(256) void wconv_kernel(const float* __restrict__ wfc,
                                                    _Float16* __restrict__ wh) {
    int idx = blockIdx.x * 256 + threadIdx.x;   // 0..4095 (n*32+kb)
    int n  = idx >> 5;
    int kb = idx & 31;
    const float* p = wfc + (size_t)n * IN_DIM + kb * 8;
    float4 v0 = *(const float4*)p;
    float4 v1 = *(const float4*)(p + 4);
    half8_t hv = {(_Float16)v0.x, (_Float16)v0.y, (_Float16)v0.z, (_Float16)v0.w,
                  (_Float16)v1.x, (_Float16)v1.y, (_Float16)v1.z, (_Float16)v1.w};
    *(half8_t*)&wh[(size_t)(n * 32 + (kb ^ (n & 7))) * 8] = hv;
}

// --- K1: z = h @ W_fc.T via mfma_f32_16x16x32_f16, fused a1/a2, f16 z -------
// block: 512 thr = 8 waves, tile 256 rows. Wave w owns rows {w*16..+15} and
// {128+w*16..+15}, all 128 cols. A-frags straight from global (32B/lane);
// B: 64KB pre-swizzled f16 LDS copy, one barrier, K-loop barrier-free.
__global__ __launch_bounds__(512, 4) void gemm_kernel(const float* __restrict__ h,
                                                      const _Float16* __restrict__ wh,
                                                      const float* __restrict__ wattn,
                                                      _Float16* __restrict__ zh,
                                                      float* __restrict__ a1,
                                                      float* __restrict__ a2, int M) {
    __shared__ _Float16 Bs[IN_DIM * OUT_DIM];   // 64 KB

    const int t    = threadIdx.x;
    const int lane = t & 63;
    const int w    = t >> 6;          // 0..7
    const int quad = lane >> 4;       // 0..3
    const int l15  = lane & 15;
    const int m0   = blockIdx.x * 256;

    // ---- stage B: linear 16B copies of pre-swizzled f16 W ----
#pragma unroll
    for (int i = 0; i < 8; ++i) {
        int idx = t + i * 512;        // granule 0..4095
        *(half8_t*)&Bs[(size_t)idx * 8] = *(const half8_t*)&wh[(size_t)idx * 8];
    }
    __syncthreads();   // the ONLY block-wide barrier

    // lane's two A rows (clamped; OOB rows computed but never stored)
    const int lrow0 = w * 16 + l15;
    const int lrow1 = 128 + w * 16 + l15;
    const int g0 = (m0 + lrow0 < M) ? (m0 + lrow0) : (M - 1);
    const int g1 = (m0 + lrow1 < M) ? (m0 + lrow1) : (M - 1);
    const float* arow0 = h + (size_t)g0 * IN_DIM;
    const float* arow1 = h + (size_t)g1 * IN_DIM;

    f32x4 acc[2][8] = {};   // [row-set][ni]

#pragma unroll
    for (int kc = 0; kc < 8; ++kc) {
        // A-frags straight from global: 8 fp32 = 32 B contiguous per lane
        float4 u0 = *(const float4*)(arow0 + kc * 32 + quad * 8);
        float4 u1 = *(const float4*)(arow0 + kc * 32 + quad * 8 + 4);
        float4 v0 = *(const float4*)(arow1 + kc * 32 + quad * 8);
        float4 v1 = *(const float4*)(arow1 + kc * 32 + quad * 8 + 4);
        half8_t a0 = {(_Float16)u0.x, (_Float16)u0.y, (_Float16)u0.z, (_Float16)u0.w,
                      (_Float16)u1.x, (_Float16)u1.y, (_Float16)u1.z, (_Float16)u1.w};
        half8_t a1f = {(_Float16)v0.x, (_Float16)v0.y, (_Float16)v0.z, (_Float16)v0.w,
                       (_Float16)v1.x, (_Float16)v1.y, (_Float16)v1.z, (_Float16)v1.w};
#pragma unroll
        for (int ni = 0; ni < 8; ++ni) {
            int n = ni * 16 + l15;
            int g = (kc * 4 + quad) ^ (n & 7);
            half8_t b = *(const half8_t*)&Bs[(size_t)(n * 32 + g) * 8];
            acc[0][ni] = __builtin_amdgcn_mfma_f32_16x16x32_f16(a0,  b, acc[0][ni], 0, 0, 0);
            acc[1][ni] = __builtin_amdgcn_mfma_f32_16x16x32_f16(a1f, b, acc[1][ni], 0, 0, 0);
        }
    }

    // ---- fused a1/a2 + z stores (C/D layout col=l15, row=quad*4+r) ----
    float w1v[8], w2v[8];
#pragma unroll
    for (int ni = 0; ni < 8; ++ni) {
        int col = ni * 16 + l15;
        w1v[ni] = wattn[col];
        w2v[ni] = wattn[OUT_DIM + col];
    }
#pragma unroll
    for (int s = 0; s < 2; ++s) {
#pragma unroll
        for (int r = 0; r < 4; ++r) {
            float p1 = 0.f, p2 = 0.f;
#pragma unroll
            for (int ni = 0; ni < 8; ++ni) {
                p1 += acc[s][ni][r] * w1v[ni];
                p2 += acc[s][ni][r] * w2v[ni];
            }
#pragma unroll
            for (int o = 8; o; o >>= 1) {   // reduce across the 16-lane col group
                p1 += __shfl_xor(p1, o);
                p2 += __shfl_xor(p2, o);
            }
            int row = m0 + s * 128 + w * 16 + quad * 4 + r;
            if (row < M) {
                if (l15 == 0) { a1[row] = p1; a2[row] = p2; }
#pragma unroll
                for (int ni = 0; ni < 8; ++ni)
                    zh[(size_t)row * OUT_DIM + ni * 16 + l15] = (_Float16)acc[s][ni][r];
            }
        }
    }
}

// --- K4: histogram of dst ---------------------------------------------------
__global__ void hist_kernel(const int* __restrict__ dst, int* __restrict__ cnt, int E) {
    int i = blockIdx.x * 256 + threadIdx.x;
    if (i < E) atomicAdd(&cnt[dst[i]], 1);
}

// --- K5a: per-block reduce of cnt -> bsum[196] ------------------------------
__global__ __launch_bounds__(256) void scan_reduce_kernel(const int* __restrict__ cnt,
                                                          int* __restrict__ bsum, int NW) {
    __shared__ int sm[4];
    const int t = threadIdx.x;
    const int i = blockIdx.x * 256 + t;
    int v = (i < NW) ? cnt[i] : 0;
#pragma unroll
    for (int o = 32; o; o >>= 1) v += __shfl_xor(v, o);
    if ((t & 63) == 0) sm[t >> 6] = v;
    __syncthreads();
    if (t == 0) bsum[blockIdx.x] = sm[0] + sm[1] + sm[2] + sm[3];
}

// --- K5b: exclusive scan of <=256 block partials (one block) ----------------
__global__ __launch_bounds__(256) void scan_partials_kernel(const int* __restrict__ bsum,
                                                            int* __restrict__ bpre, int nb,
                                                            int* __restrict__ off, int NW, int E) {
    __shared__ int sm[256];
    const int t = threadIdx.x;
    int v = (t < nb) ? bsum[t] : 0;
    sm[t] = v;
    __syncthreads();
    for (int d = 1; d < 256; d <<= 1) {
        int u = (t >= d) ? sm[t - d] : 0;
        __syncthreads();
        sm[t] += u;
        __syncthreads();
    }
    if (t < nb) bpre[t] = sm[t] - v;   // exclusive prefix of block t
    if (t == 0) off[NW] = E;
}

// --- K5c: block-local exclusive scan + block offset -> off, cur -------------
__global__ __launch_bounds__(256) void scan_final_kernel(const int* __restrict__ cnt,
                                                         const int* __restrict__ bpre,
                                                         int* __restrict__ off,
                                                         int* __restrict__ cur, int NW) {
    __shared__ int sm[256];
    const int t = threadIdx.x;
    const int i = blockIdx.x * 256 + t;
    int v = (i < NW) ? cnt[i] : 0;
    sm[t] = v;
    __syncthreads();
    for (int d = 1; d < 256; d <<= 1) {
        int u = (t >= d) ? sm[t - d] : 0;
        __syncthreads();
        sm[t] += u;
        __syncthreads();
    }
    int ex = sm[t] - v + bpre[blockIdx.x];
    if (i < NW) { off[i] = ex; cur[i] = ex; }
}

// --- K6: scatter edges into CSR order, computing masked leaky scores --------
__global__ void scatter_kernel(const int* __restrict__ src, const int* __restrict__ dst,
                               const float* __restrict__ a1, const float* __restrict__ a2,
                               int* __restrict__ cur, int* __restrict__ esrc,
                               float* __restrict__ evals, int E) {
    int i = blockIdx.x * 256 + threadIdx.x;
    if (i >= E) return;
    int s = src[i];
    int d = dst[i];
    float x = a1[s] + a2[d];
    float e = x > 0.f ? x : 0.01f * x;          // leaky_relu(0.01)
    if (e == 0.f) e = -1000.f;                  // DGL zero-mask emulation
    int pos = atomicAdd(&cur[d], 1);
    esrc[pos]  = s;
    evals[pos] = e;
}

// --- K7: per-dst softmax + weighted aggregation (one wave per dst) ----------
// Fast path (deg<=64): evals/esrc register-resident, weights broadcast by
// shfl, z-row (f16, 256B) loads unrolled x4 for memory-level parallelism.
__global__ __launch_bounds__(256) void agg_kernel(const _Float16* __restrict__ zh,
                                                  const int* __restrict__ off,
                                                  const int* __restrict__ esrc,
                                                  const float* __restrict__ evals,
                                                  float* __restrict__ out, int NW) {
    const int lane = threadIdx.x & 63;
    const int w = blockIdx.x * 4 + (threadIdx.x >> 6);
    if (w >= NW) return;
    const int beg = off[w];
    const int end = off[w + 1];
    const int cnt = end - beg;

    float2 acc = make_float2(0.f, 0.f);

    if (cnt <= 64) {
        float ev = (lane < cnt) ? evals[beg + lane] : -INFINITY;
        int   se = (lane < cnt) ? esrc[beg + lane] : 0;
        float mx = ev;
#pragma unroll
        for (int o = 32; o; o >>= 1) mx = fmaxf(mx, __shfl_xor(mx, o));
        float ex = (lane < cnt) ? __expf(ev - mx) : 0.f;
        float s = ex;
#pragma unroll
        for (int o = 32; o; o >>= 1) s += __shfl_xor(s, o);
        ex *= (cnt > 0) ? (1.0f / s) : 0.f;      // per-lane alpha

        int j = 0;
        for (; j + 4 <= cnt; j += 4) {
            int   s0 = __shfl(se, j),     s1 = __shfl(se, j + 1);
            int   s2 = __shfl(se, j + 2), s3 = __shfl(se, j + 3);
            float w0 = __shfl(ex, j),     w1 = __shfl(ex, j + 1);
            float w2 = __shfl(ex, j + 2), w3 = __shfl(ex, j + 3);
            half2_t z0 = *(const half2_t*)(zh + (size_t)s0 * OUT_DIM + lane * 2);
            half2_t z1 = *(const half2_t*)(zh + (size_t)s1 * OUT_DIM + lane * 2);
            half2_t z2 = *(const half2_t*)(zh + (size_t)s2 * OUT_DIM + lane * 2);
            half2_t z3 = *(const half2_t*)(zh + (size_t)s3 * OUT_DIM + lane * 2);
            acc.x += w0 * (float)z0[0] + w1 * (float)z1[0] + w2 * (float)z2[0] + w3 * (float)z3[0];
            acc.y += w0 * (float)z0[1] + w1 * (float)z1[1] + w2 * (float)z2[1] + w3 * (float)z3[1];
        }
        for (; j < cnt; ++j) {
            int   sj = __shfl(se, j);
            float wj = __shfl(ex, j);
            half2_t zj = *(const half2_t*)(zh + (size_t)sj * OUT_DIM + lane * 2);
            acc.x += wj * (float)zj[0];
            acc.y += wj * (float)zj[1];
        }
    } else {
        // rare fallback: degree > 64
        float mx = -INFINITY;
        for (int j = beg + lane; j < end; j += 64) mx = fmaxf(mx, evals[j]);
#pragma unroll
        for (int o = 32; o; o >>= 1) mx = fmaxf(mx, __shfl_xor(mx, o));
        float s = 0.f;
        for (int j = beg + lane; j < end; j += 64) s += __expf(evals[j] - mx);
#pragma unroll
        for (int o = 32; o; o >>= 1) s += __shfl_xor(s, o);
        const float inv = 1.0f / s;
        for (int j = beg; j < end; ++j) {
            int   sidx = esrc[j];
            float wgt  = __expf(evals[j] - mx) * inv;
            half2_t zr = *(const half2_t*)(zh + (size_t)sidx * OUT_DIM + lane * 2);
            acc.x += wgt * (float)zr[0];
            acc.y += wgt * (float)zr[1];
        }
    }
    ((float2*)(out + (size_t)w * OUT_DIM))[lane] = acc;   // always written (zeros if empty)
}

// ---------------------------------------------------------------------------
extern "C" void kernel_launch(void* const* d_in, const int* in_sizes, int n_in,
                              void* d_out, int out_size, void* d_ws, size_t ws_size,
                              hipStream_t stream) {
    const float* h     = (const float*)d_in[0];
    const int*   src   = (const int*)d_in[1];
    const int*   dst   = (const int*)d_in[2];
    const float* wfc   = (const float*)d_in[3];
    const float* wattn = (const float*)d_in[4];
    float*       out   = (float*)d_out;

    const int N  = in_sizes[0] / IN_DIM;   // 100000
    const int E  = in_sizes[1];            // 500000
    const int NW = out_size / OUT_DIM;     // 50000
    const int nb = (NW + 255) / 256;       // 196 scan blocks (<=256 required)

    // workspace layout
    _Float16* zh = (_Float16*)d_ws;               // N*128 f16
    _Float16* wh = zh + (size_t)N * OUT_DIM;      // 256*128 f16 (swizzled)
    float* a1    = (float*)(wh + IN_DIM * OUT_DIM);  // N
    float* a2    = a1 + N;                        // N
    int*   cnt   = (int*)(a2 + N);                // NW
    int*   off   = cnt + NW;                      // NW+1
    int*   cur   = off + NW + 1;                  // NW
    int*   esrc  = cur + NW;                      // E
    float* evals = (float*)(esrc + E);            // E
    int*   bsum  = (int*)(evals + E);             // nb
    int*   bpre  = bsum + nb;                     // nb

    wconv_kernel<<<16, 256, 0, stream>>>(wfc, wh);
    gemm_kernel<<<(N + 255) / 256, 512, 0, stream>>>(h, wh, wattn, zh, a1, a2, N);
    hipMemsetAsync(cnt, 0, (size_t)NW * sizeof(int), stream);
    hist_kernel<<<(E + 255) / 256, 256, 0, stream>>>(dst, cnt, E);
    scan_reduce_kernel<<<nb, 256, 0, stream>>>(cnt, bsum, NW);
    scan_partials_kernel<<<1, 256, 0, stream>>>(bsum, bpre, nb, off, NW, E);
    scan_final_kernel<<<nb, 256, 0, stream>>>(cnt, bpre, off, cur, NW);
    scatter_kernel<<<(E + 255) / 256, 256, 0, stream>>>(src, dst, a1, a2, cur, esrc, evals, E);
    agg_kernel<<<(NW + 3) / 4, 256, 0, stream>>>(zh, off, esrc, evals, out, NW);
}